// Round 3
// baseline (2195.229 us; speedup 1.0000x reference)
//
#include <hip/hip_runtime.h>
#include <hip/hip_bf16.h>

typedef __attribute__((ext_vector_type(8))) short short8;
typedef __attribute__((ext_vector_type(4))) float f32x4;
typedef __hip_bfloat16 bf16;

__device__ __forceinline__ short f2bs(float f) {
    bf16 b = __float2bfloat16(f);
    return *reinterpret_cast<const short*>(&b);
}
__device__ __forceinline__ float bs2f(short s) {
    bf16 b = *reinterpret_cast<const bf16*>(&s);
    return __bfloat162float(b);
}
// dtype-flag-dispatched scalar load (flag=1: bf16, flag=0: fp32)
__device__ __forceinline__ float ldf(const void* p, int i, int flag) {
    return flag ? bs2f(((const short*)p)[i]) : ((const float*)p)[i];
}
__device__ __forceinline__ short ldbits(const void* p, int i, int flag) {
    return flag ? ((const short*)p)[i] : f2bs(((const float*)p)[i]);
}
__device__ __forceinline__ void stf(void* p, int i, float v, int flag) {
    if (flag) ((bf16*)p)[i] = __float2bfloat16(v);
    else ((float*)p)[i] = v;
}
__device__ __forceinline__ float nz(float v) { return (v == v) ? v : 0.f; }
__device__ __forceinline__ float siluf(float v) {
    float t = __expf(fminf(fmaxf(-v, -80.f), 80.f));
    return v / (1.f + t);
}
__device__ __forceinline__ float sigmf(float v) {
    float t = __expf(fminf(fmaxf(-v, -80.f), 80.f));
    return 1.f / (1.f + t);
}

// ---------------------------------------------------------------------------
// detect: bf16-packed vs fp32 input world, from low half-words of h
// ---------------------------------------------------------------------------
__global__ void detect_kernel(const unsigned int* __restrict__ hw, int* __restrict__ flag) {
    unsigned int w = hw[threadIdx.x];
    unsigned int e = (w >> 7) & 0xFF;  // exponent of low half-word viewed as bf16
    bool ok = (e >= 113 && e <= 135);  // |v| in [2^-14, 2^8]: true for N(0,1) bf16
    unsigned long long m = __ballot(ok);
    if (threadIdx.x == 0) *flag = (__popcll(m) >= 32) ? 1 : 0;
}

// ---------------------------------------------------------------------------
// prep: canonicalize weights. Transposed bf16: W1t[128x288](K pad 258->288),
// W2t/cW1t[128x128], iW1t[64x128]. fp32 copies: bias block + nW1/nW2/vW1.
// ---------------------------------------------------------------------------
__global__ void prep_kernel(
    const void* eW1, const void* eW2, const void* cW1, const void* iW1,
    const void* eb1, const void* eb2, const void* cb1, const void* cw2,
    const void* ib1, const void* iw2, const void* ib2, const void* nb1,
    const void* nb2, const void* vb1, const void* vW2,
    const void* nW1, const void* nW2, const void* vW1,
    short* __restrict__ W1t, short* __restrict__ W2t,
    short* __restrict__ cW1t, short* __restrict__ iW1t,
    float* __restrict__ biasblk, float* __restrict__ nW1f,
    float* __restrict__ nW2f, float* __restrict__ vW1f,
    const int* __restrict__ flagp) {
    const int flag = *flagp;
    int i = blockIdx.x * 256 + threadIdx.x;
    if (i < 36864) { int n = i / 288, k = i % 288; W1t[i] = (k < 258) ? ldbits(eW1, k * 128 + n, flag) : (short)0; return; }
    i -= 36864;
    if (i < 16384) { int n = i / 128, k = i % 128; W2t[i] = ldbits(eW2, k * 128 + n, flag); return; }
    i -= 16384;
    if (i < 16384) { int n = i / 128, k = i % 128; cW1t[i] = ldbits(cW1, k * 128 + n, flag); return; }
    i -= 16384;
    if (i < 8192) { int n = i / 128, k = i % 128; iW1t[i] = ldbits(iW1, k * 64 + n, flag); return; }
    i -= 8192;
    if (i < 1156) {
        float v;
        if (i < 128) v = ldf(eb1, i, flag);
        else if (i < 256) v = ldf(eb2, i - 128, flag);
        else if (i < 384) v = ldf(cb1, i - 256, flag);
        else if (i < 512) v = ldf(cw2, i - 384, flag);
        else if (i < 576) v = ldf(ib1, i - 512, flag);
        else if (i < 640) v = ldf(iw2, i - 576, flag);
        else if (i < 644) v = (i == 640) ? ldf(ib2, 0, flag) : 0.f;
        else if (i < 772) v = ldf(nb1, i - 644, flag);
        else if (i < 900) v = ldf(nb2, i - 772, flag);
        else if (i < 1028) v = ldf(vb1, i - 900, flag);
        else v = ldf(vW2, i - 1028, flag);
        biasblk[i] = v;
        return;
    }
    i -= 1156;
    if (i < 32768) { nW1f[i] = ldf(nW1, i, flag); return; }
    i -= 32768;
    if (i < 16384) { nW2f[i] = ldf(nW2, i, flag); return; }
    i -= 16384;
    if (i < 16384) { vW1f[i] = ldf(vW1, i, flag); }
}

// ---------------------------------------------------------------------------
// convert h -> canonical bf16 hb
// ---------------------------------------------------------------------------
__global__ void convh_kernel(const void* __restrict__ h, short* __restrict__ hb,
                             const int* __restrict__ flagp, int n) {
    const int flag = *flagp;
    int i = blockIdx.x * 256 + threadIdx.x;
    if (i < n) hb[i] = ldbits(h, i, flag);
}

// ---------------------------------------------------------------------------
// vel: vel_scale = silu(h@vW1+vb1)@vW2 ; v_out = v_init * vel_scale
// ---------------------------------------------------------------------------
__global__ __launch_bounds__(128) void vel_kernel(
    const short* __restrict__ hb, const void* __restrict__ v_init,
    const float* __restrict__ vW1f, const float* __restrict__ vb1f,
    const float* __restrict__ vW2f,
    float* __restrict__ vout_f32, void* __restrict__ out, int vbase,
    const int* __restrict__ flagp) {
    const int flag = *flagp;
    __shared__ float hs[128];
    __shared__ float red[128];
    const int n = blockIdx.x, j = threadIdx.x;
    hs[j] = bs2f(hb[n * 128 + j]);
    __syncthreads();
    float acc = vb1f[j];
#pragma unroll 8
    for (int k = 0; k < 128; ++k) acc += hs[k] * vW1f[k * 128 + j];
    red[j] = siluf(nz(acc)) * vW2f[j];
    __syncthreads();
    for (int s = 64; s > 0; s >>= 1) {
        if (j < s) red[j] += red[j + s];
        __syncthreads();
    }
    if (j < 3) {
        float v = ldf(v_init, n * 3 + j, flag) * red[0];
        v = nz(v);
        vout_f32[n * 3 + j] = v;
        stf(out, vbase + n * 3 + j, v, flag);
    }
}

// ---------------------------------------------------------------------------
// edge kernel: fused edge MLP + inf + coord + scatter.
// block = 256 thr = 4 waves; each wave owns 16 edges. MFMA 16x16x32 bf16.
// A layout: A[m=lane&15][k=quad*8+j]; B: B[k=quad*8+j][n=lane&15];
// C: C[row=quad*4+reg][col=lane&15]
// ---------------------------------------------------------------------------
__global__ __launch_bounds__(256) void edge_kernel(
    const short* __restrict__ hb, const void* __restrict__ x,
    const void* __restrict__ eattr,
    const int* __restrict__ erow, const int* __restrict__ ecol,
    const short* __restrict__ W1t, const short* __restrict__ W2t,
    const short* __restrict__ cW1t, const short* __restrict__ iW1t,
    const float* __restrict__ b1f, const float* __restrict__ b2f,
    const float* __restrict__ cb1f, const float* __restrict__ cw2f,
    const float* __restrict__ ib1f, const float* __restrict__ iw2f,
    const float* __restrict__ ib2f,
    float* __restrict__ m_i, float* __restrict__ agg_x, int* __restrict__ deg,
    int E, const int* __restrict__ flagp) {
    const int flag = *flagp;
    __shared__ __align__(16) short tiles[4][16 * 136];
    const int tid = threadIdx.x;
    const int wv = tid >> 6;
    const int lane = tid & 63;
    const int n15 = lane & 15;
    const int quad = lane >> 4;
    const int wb = blockIdx.x * 64 + wv * 16;

    const int e = wb + n15;
    const int eL = (e < E) ? e : (E - 1);
    const int row_e = erow[eL];
    const int col_e = ecol[eL];

    float dist = 0.f;
#pragma unroll
    for (int d = 0; d < 3; ++d) {
        float xd = ldf(x, row_e * 3 + d, flag) - ldf(x, col_e * 3 + d, flag);
        dist += xd * xd;
    }
    dist = nz(dist);
    const float attr = nz(ldf(eattr, eL, flag));

    // ---- GEMM1: ef[16 x 288] @ W1 -> hidden1 [16 x 128]
    f32x4 acc1[8];
#pragma unroll
    for (int nt = 0; nt < 8; ++nt) acc1[nt] = (f32x4){0.f, 0.f, 0.f, 0.f};
#pragma unroll
    for (int kc = 0; kc < 9; ++kc) {
        short8 a;
        if (kc < 4) {
            a = *(const short8*)(hb + row_e * 128 + kc * 32 + quad * 8);
        } else if (kc < 8) {
            a = *(const short8*)(hb + col_e * 128 + (kc - 4) * 32 + quad * 8);
        } else {
#pragma unroll
            for (int t = 0; t < 8; ++t) a[t] = 0;
            if (quad == 0) { a[0] = f2bs(dist); a[1] = f2bs(attr); }
        }
#pragma unroll
        for (int nt = 0; nt < 8; ++nt) {
            short8 b = *(const short8*)(W1t + (nt * 16 + n15) * 288 + kc * 32 + quad * 8);
            acc1[nt] = __builtin_amdgcn_mfma_f32_16x16x32_bf16(a, b, acc1[nt], 0, 0, 0);
        }
    }

    // hidden1 = silu(acc1 + b1) -> LDS tile (C-layout -> A-layout transpose)
    short* tile = tiles[wv];
#pragma unroll
    for (int nt = 0; nt < 8; ++nt) {
        float bv = b1f[nt * 16 + n15];
#pragma unroll
        for (int r = 0; r < 4; ++r) {
            float v = nz(acc1[nt][r] + bv);
            tile[(quad * 4 + r) * 136 + nt * 16 + n15] = f2bs(siluf(v));
        }
    }
    __syncthreads();

    // ---- GEMM2: hidden1 @ W2 -> m_ij
    f32x4 acc2[8];
#pragma unroll
    for (int nt = 0; nt < 8; ++nt) acc2[nt] = (f32x4){0.f, 0.f, 0.f, 0.f};
#pragma unroll
    for (int kc = 0; kc < 4; ++kc) {
        short8 a = *(const short8*)(tile + n15 * 136 + kc * 32 + quad * 8);
#pragma unroll
        for (int nt = 0; nt < 8; ++nt) {
            short8 b = *(const short8*)(W2t + (nt * 16 + n15) * 128 + kc * 32 + quad * 8);
            acc2[nt] = __builtin_amdgcn_mfma_f32_16x16x32_bf16(a, b, acc2[nt], 0, 0, 0);
        }
    }
    float mv[8][4];
#pragma unroll
    for (int nt = 0; nt < 8; ++nt) {
        float bv = b2f[nt * 16 + n15];
#pragma unroll
        for (int r = 0; r < 4; ++r) mv[nt][r] = siluf(nz(acc2[nt][r] + bv));
    }
    __syncthreads();
#pragma unroll
    for (int nt = 0; nt < 8; ++nt)
#pragma unroll
        for (int r = 0; r < 4; ++r)
            tile[(quad * 4 + r) * 136 + nt * 16 + n15] = f2bs(mv[nt][r]);
    __syncthreads();

    // ---- GEMM3 (coord hidden) + GEMM4 (inf hidden), shared A frags
    f32x4 acc3[8];
    f32x4 acc4[4];
#pragma unroll
    for (int nt = 0; nt < 8; ++nt) acc3[nt] = (f32x4){0.f, 0.f, 0.f, 0.f};
#pragma unroll
    for (int nt = 0; nt < 4; ++nt) acc4[nt] = (f32x4){0.f, 0.f, 0.f, 0.f};
#pragma unroll
    for (int kc = 0; kc < 4; ++kc) {
        short8 a = *(const short8*)(tile + n15 * 136 + kc * 32 + quad * 8);
#pragma unroll
        for (int nt = 0; nt < 8; ++nt) {
            short8 b = *(const short8*)(cW1t + (nt * 16 + n15) * 128 + kc * 32 + quad * 8);
            acc3[nt] = __builtin_amdgcn_mfma_f32_16x16x32_bf16(a, b, acc3[nt], 0, 0, 0);
        }
#pragma unroll
        for (int nt = 0; nt < 4; ++nt) {
            short8 b = *(const short8*)(iW1t + (nt * 16 + n15) * 128 + kc * 32 + quad * 8);
            acc4[nt] = __builtin_amdgcn_mfma_f32_16x16x32_bf16(a, b, acc4[nt], 0, 0, 0);
        }
    }

    // ---- epilogues: phi = silu(coord_h)@cw2 ; e = sigmoid(silu(inf_h)@iw2+ib2)
    float php[4] = {0.f, 0.f, 0.f, 0.f};
    float inp[4] = {0.f, 0.f, 0.f, 0.f};
#pragma unroll
    for (int nt = 0; nt < 8; ++nt) {
        float cb = cb1f[nt * 16 + n15];
        float cw = cw2f[nt * 16 + n15];
#pragma unroll
        for (int r = 0; r < 4; ++r) php[r] += siluf(nz(acc3[nt][r] + cb)) * cw;
    }
#pragma unroll
    for (int nt = 0; nt < 4; ++nt) {
        float ib = ib1f[nt * 16 + n15];
        float iw = iw2f[nt * 16 + n15];
#pragma unroll
        for (int r = 0; r < 4; ++r) inp[r] += siluf(nz(acc4[nt][r] + ib)) * iw;
    }
#pragma unroll
    for (int mk = 1; mk < 16; mk <<= 1) {
#pragma unroll
        for (int r = 0; r < 4; ++r) {
            php[r] += __shfl_xor(php[r], mk);
            inp[r] += __shfl_xor(inp[r], mk);
        }
    }
    const float ib2s = ib2f[0];
    float eij[4];
#pragma unroll
    for (int r = 0; r < 4; ++r) eij[r] = sigmf(nz(inp[r] + ib2s));

    int err[4], ecc[4];
    bool msk[4];
#pragma unroll
    for (int r = 0; r < 4; ++r) {
        err[r] = __shfl(row_e, quad * 4 + r);
        ecc[r] = __shfl(col_e, quad * 4 + r);
        msk[r] = (wb + quad * 4 + r) < E;
    }

    // ---- scatter m_i += e * m_ij
#pragma unroll
    for (int nt = 0; nt < 8; ++nt) {
#pragma unroll
        for (int r = 0; r < 4; ++r) {
            if (msk[r]) atomicAdd(&m_i[err[r] * 128 + nt * 16 + n15], nz(eij[r] * mv[nt][r]));
        }
    }

    // ---- scatter agg_x += e*phi*x_diff ; deg += 1 (one lane per edge)
    if (n15 == 0) {
#pragma unroll
        for (int r = 0; r < 4; ++r) {
            if (!msk[r]) continue;
            float s = eij[r] * php[r];
#pragma unroll
            for (int d = 0; d < 3; ++d) {
                float xd = ldf(x, err[r] * 3 + d, flag) - ldf(x, ecc[r] * 3 + d, flag);
                atomicAdd(&agg_x[err[r] * 3 + d], nz(s * xd));
            }
            atomicAdd(&deg[err[r]], 1);
        }
    }
}

// ---------------------------------------------------------------------------
// node: h_out = silu([h,m_i]@nW1+nb1)@nW2+nb2 ; x_out
// ---------------------------------------------------------------------------
__global__ __launch_bounds__(128) void node_kernel(
    const short* __restrict__ hb, const void* __restrict__ x,
    const float* __restrict__ m_i, const float* __restrict__ agg_x,
    const int* __restrict__ deg, const float* __restrict__ vout_f32,
    const float* __restrict__ nW1f, const float* __restrict__ nb1f,
    const float* __restrict__ nW2f, const float* __restrict__ nb2f,
    void* __restrict__ out, int xbase, float inv_nm1,
    const int* __restrict__ flagp) {
    const int flag = *flagp;
    __shared__ float nin[256];
    __shared__ float hid[128];
    const int n = blockIdx.x, j = threadIdx.x;
    nin[j] = bs2f(hb[n * 128 + j]);
    nin[128 + j] = nz(m_i[n * 128 + j]);
    __syncthreads();
    float acc = nb1f[j];
#pragma unroll 8
    for (int k = 0; k < 256; ++k) acc += nin[k] * nW1f[k * 128 + j];
    hid[j] = siluf(nz(acc));
    __syncthreads();
    float o = nb2f[j];
#pragma unroll 8
    for (int k = 0; k < 128; ++k) o += hid[k] * nW2f[k * 128 + j];
    stf(out, n * 128 + j, nz(o), flag);
    if (j < 3) {
        float xv = ldf(x, n * 3 + j, flag);
        float xo = (deg[n] > 0)
                       ? xv + nz(vout_f32[n * 3 + j]) + nz(agg_x[n * 3 + j]) * inv_nm1
                       : xv;
        stf(out, xbase + n * 3 + j, nz(xo), flag);
    }
}

// ---------------------------------------------------------------------------
extern "C" void kernel_launch(void* const* d_in, const int* in_sizes, int n_in,
                              void* d_out, int out_size, void* d_ws, size_t ws_size,
                              hipStream_t stream) {
    const void* h = d_in[0];
    const void* x = d_in[1];
    const void* eattr = d_in[2];
    const void* v_init = d_in[3];
    const int* eidx = (const int*)d_in[4];

    const int N = in_sizes[0] / 128;
    const int E = in_sizes[4] / 2;
    const int* erow = eidx;
    const int* ecol = eidx + E;

    // ws layout (byte offsets, all 16B aligned)
    char* ws = (char*)d_ws;
    int* flag = (int*)ws;                                  // 4 B (pad to 256)
    short* W1t = (short*)(ws + 256);                       // 73728
    short* W2t = (short*)(ws + 73984);                     // 32768
    short* cW1t = (short*)(ws + 106752);                   // 32768
    short* iW1t = (short*)(ws + 139520);                   // 16384
    float* biasblk = (float*)(ws + 155904);                // 4624 (pad 4864)
    float* nW1f = (float*)(ws + 160768);                   // 131072
    float* nW2f = (float*)(ws + 291840);                   // 65536
    float* vW1f = (float*)(ws + 357376);                   // 65536
    short* hb = (short*)(ws + 422912);                     // N*256 B
    size_t off = 422912 + (size_t)N * 256;
    float* vout_f32 = (float*)(ws + off); off += (size_t)N * 12;
    size_t zero_off = off;
    float* agg_x = (float*)(ws + off); off += (size_t)N * 12;
    int* deg = (int*)(ws + off); off += (size_t)N * 4;
    float* m_i = (float*)(ws + off); off += (size_t)N * 512;
    size_t zero_bytes = off - zero_off;

    float* b1f = biasblk + 0;
    float* b2f = biasblk + 128;
    float* cb1f = biasblk + 256;
    float* cw2f = biasblk + 384;
    float* ib1f = biasblk + 512;
    float* iw2f = biasblk + 576;
    float* ib2f = biasblk + 640;
    float* nb1f = biasblk + 644;
    float* nb2f = biasblk + 772;
    float* vb1f = biasblk + 900;
    float* vW2f = biasblk + 1028;

    hipMemsetAsync((void*)(ws + zero_off), 0, zero_bytes, stream);

    detect_kernel<<<1, 64, 0, stream>>>((const unsigned int*)h, flag);

    const int prep_elems = 36864 + 16384 + 16384 + 8192 + 1156 + 32768 + 16384 + 16384;
    prep_kernel<<<(prep_elems + 255) / 256, 256, 0, stream>>>(
        d_in[5], d_in[7], d_in[9], d_in[12],
        d_in[6], d_in[8], d_in[10], d_in[11], d_in[13], d_in[14], d_in[15],
        d_in[17], d_in[19], d_in[21], d_in[22],
        d_in[16], d_in[18], d_in[20],
        W1t, W2t, cW1t, iW1t, biasblk, nW1f, nW2f, vW1f, flag);

    convh_kernel<<<(N * 128 + 255) / 256, 256, 0, stream>>>(h, hb, flag, N * 128);

    vel_kernel<<<N, 128, 0, stream>>>(hb, v_init, vW1f, vb1f, vW2f,
                                      vout_f32, d_out, N * 131, flag);

    edge_kernel<<<(E + 63) / 64, 256, 0, stream>>>(
        hb, x, eattr, erow, ecol, W1t, W2t, cW1t, iW1t,
        b1f, b2f, cb1f, cw2f, ib1f, iw2f, ib2f, m_i, agg_x, deg, E, flag);

    node_kernel<<<N, 128, 0, stream>>>(hb, x, m_i, agg_x, deg, vout_f32,
                                       nW1f, nb1f, nW2f, nb2f, d_out, N * 128,
                                       1.0f / (float)(N - 1), flag);
}